// Round 1
// baseline (413.530 us; speedup 1.0000x reference)
//
#include <hip/hip_runtime.h>

// CostVolume2D: out[b, d+48, h, w] = (1/64) * sum_c l[b,c,h,w] * r[b,c,h,w-d]
// B=4, C=64, H=256, W=512, max_disp=48 -> 97 disparity planes.
// Identity: with u = w-d, out is the band |w-u|<=48 of G = L^T R per (b,h):
// a banded GEMM over K=C=64 -> bf16 MFMA 16x16x32, fp32 accumulate.

#define B_  4
#define C_  64
#define H_  256
#define W_  512
#define MD  48
#define ND  97          // 2*MD+1 disparity planes
#define WT  64          // w-tile per block
#define RT  160         // WT + 2*MD  (r-tile incl. halo)
#define HW  (H_ * W_)

typedef __attribute__((ext_vector_type(8))) short  short8;   // 8 bf16 = 4 VGPR
typedef __attribute__((ext_vector_type(4))) float  floatx4;

__device__ __forceinline__ unsigned f2bf(float f) {
    // fp32 -> bf16 round-to-nearest-even, result in low 16 bits
    unsigned u = __builtin_bit_cast(unsigned, f);
    return (u + 0x7FFFu + ((u >> 16) & 1u)) >> 16;
}

// LDS: staging tiles (bf16, fragment-linear) aliased with the fp32 output
// staging buffer (used strictly after a barrier once MFMA reads are done).
// Fragment-linear layout: 16B chunk index = ((row>>4)*8 + (c>>3))*16 + (row&15),
// element j = c&7.  A lane's ds_read_b128 for an MFMA fragment is then one
// contiguous 16B chunk -> conflict-free wave pattern.
union SM {
    struct {
        short l[WT * C_];    // 8 KiB
        short r[RT * C_];    // 20 KiB
    } st;
    float out_s[ND * 68];    // 97 rows x (64+4 pad) fp32 = 25.8 KiB
};

__global__ __launch_bounds__(256, 4) void cost_volume_kernel(
    const float* __restrict__ L, const float* __restrict__ R,
    float* __restrict__ out)
{
    __shared__ SM sm;
    const int tid  = threadIdx.x;
    const int w0   = blockIdx.x * WT;
    const int h    = blockIdx.y;
    const int b    = blockIdx.z;
    const int lane = tid & 63;
    const int wv   = tid >> 6;          // wave id 0..3 (w row-tile)

    const size_t in_base = (((size_t)b * C_) * H_ + h) * (size_t)W_;

    // ---- stage L: 64 w x 64 c, x(1/64) folded into bf16 convert ----
    {
        const int wl = tid & 63;
        const int m  = wl & 15, wq = wl >> 4;
        const float* lp = L + in_base + w0 + wl;
        #pragma unroll
        for (int i = 0; i < 2; ++i) {
            const int cc = (tid >> 6) + 4 * i;          // c-chunk 0..7
            unsigned d[4];
            #pragma unroll
            for (int jj = 0; jj < 4; ++jj) {
                float f0 = lp[(size_t)(cc * 8 + 2 * jj)     * HW] * 0.015625f;
                float f1 = lp[(size_t)(cc * 8 + 2 * jj + 1) * HW] * 0.015625f;
                d[jj] = f2bf(f0) | (f2bf(f1) << 16);
            }
            const int chunk = (wq * 8 + cc) * 16 + m;
            *((uint4*)&sm.st.l[chunk * 8]) = make_uint4(d[0], d[1], d[2], d[3]);
        }
    }

    // ---- stage R: 160 u x 64 c (u = w0-48 .. w0+111, OOB -> 0) ----
    #pragma unroll
    for (int wc = 0; wc < 3; ++wc) {
        const int ul = wc * 64 + (tid & 63);
        if (ul < RT) {
            const int  ug = w0 - MD + ul;
            const bool ok = ((unsigned)ug < (unsigned)W_);
            const float* rp = R + in_base + ug;
            const int m = ul & 15, uq = ul >> 4;
            #pragma unroll
            for (int i = 0; i < 2; ++i) {
                const int cc = (tid >> 6) + 4 * i;
                unsigned d[4];
                #pragma unroll
                for (int jj = 0; jj < 4; ++jj) {
                    float f0 = ok ? rp[(size_t)(cc * 8 + 2 * jj)     * HW] : 0.0f;
                    float f1 = ok ? rp[(size_t)(cc * 8 + 2 * jj + 1) * HW] : 0.0f;
                    d[jj] = f2bf(f0) | (f2bf(f1) << 16);
                }
                const int chunk = (uq * 8 + cc) * 16 + m;
                *((uint4*)&sm.st.r[chunk * 8]) = make_uint4(d[0], d[1], d[2], d[3]);
            }
        }
    }
    __syncthreads();

    // ---- banded GEMM: wave wv owns w rows [w0+16*wv, +16); 7 u-tiles ----
    const int q   = lane >> 4;      // 0..3
    const int m16 = lane & 15;
    const short8* lv = (const short8*)sm.st.l;
    const short8* rv = (const short8*)sm.st.r;

    // A frag: A[m=lane&15][k=(lane>>4)*8+j], k = c (K=64 -> 2 frags)
    const short8 a0 = lv[(wv * 8 +     q) * 16 + m16];
    const short8 a1 = lv[(wv * 8 + 4 + q) * 16 + m16];

    floatx4 acc[7];
    #pragma unroll
    for (int t = 0; t < 7; ++t) {
        // B frag rows in r-tile: 16*(wv+t) + (lane&15)  (u dimension)
        const short8 b0 = rv[((wv + t) * 8 +     q) * 16 + m16];
        const short8 b1 = rv[((wv + t) * 8 + 4 + q) * 16 + m16];
        floatx4 c = {0.f, 0.f, 0.f, 0.f};
        c = __builtin_amdgcn_mfma_f32_16x16x32_bf16(a0, b0, c, 0, 0, 0);
        c = __builtin_amdgcn_mfma_f32_16x16x32_bf16(a1, b1, c, 0, 0, 0);
        acc[t] = c;
    }
    __syncthreads();   // staging LDS dead; safe to alias as out_s

    // ---- epilogue: scatter band diagonals (d = w-u) into out_s ----
    // C/D layout: col(u) = lane&15, row(w) = (lane>>4)*4 + reg
    #pragma unroll
    for (int t = 0; t < 7; ++t) {
        #pragma unroll
        for (int r = 0; r < 4; ++r) {
            const int ml    = q * 4 + r;                    // w offset in 16-row tile
            const int d_idx = ml - m16 + 96 - 16 * t;       // d + 48
            if ((unsigned)d_idx <= 96u) {
                const int w_local = wv * 16 + ml;
                sm.out_s[d_idx * 68 + w_local] = acc[t][r];
            }
        }
    }
    __syncthreads();

    // ---- coalesced write-out: 97 planes x 64 contiguous floats ----
    float* ob = out + (((size_t)b * ND) * H_ + h) * (size_t)W_ + w0;
    for (int i = tid; i < ND * WT; i += 256) {
        const int dr = i >> 6, wl = i & 63;
        ob[(size_t)dr * HW + wl] = sm.out_s[dr * 68 + wl];
    }
}

extern "C" void kernel_launch(void* const* d_in, const int* in_sizes, int n_in,
                              void* d_out, int out_size, void* d_ws, size_t ws_size,
                              hipStream_t stream) {
    const float* L = (const float*)d_in[0];
    const float* R = (const float*)d_in[1];
    float* out = (float*)d_out;
    (void)in_sizes; (void)n_in; (void)d_ws; (void)ws_size; (void)out_size;
    dim3 grid(W_ / WT, H_, B_);   // (8 w-tiles, 256 h, 4 b)
    hipLaunchKernelGGL(cost_volume_kernel, grid, dim3(256), 0, stream, L, R, out);
}

// Round 2
// 386.579 us; speedup vs baseline: 1.0697x; 1.0697x over previous
//
#include <hip/hip_runtime.h>

// CostVolume2D: out[b, d+48, h, w] = (1/64) * sum_c l[b,c,h,w] * r[b,c,h,w-d]
// B=4, C=64, H=256, W=512, 97 planes.  Band of G = L^T R per (b,h) via bf16 MFMA.
// R2: one block per (b,h) ROW (WT=512) -> zero halo overfetch; every input
// byte fetched exactly once.  1024 thr, 128 KB LDS staging aliased with a
// d-chunked output stage.

#define B_  4
#define C_  64
#define H_  256
#define W_  512
#define ND  97
#define NWT 32          // 16-wide w-tiles per row
#define HW  (H_ * W_)
#define PAD 513         // out-chunk row stride (512+1) -> conflict-free scatter
#define CH0 49          // planes in chunk 0 (chunk 1 = 48)

typedef __attribute__((ext_vector_type(8))) short  short8;
typedef __attribute__((ext_vector_type(4))) float  floatx4;

__device__ __forceinline__ unsigned f2bf(float f) {
    unsigned u = __builtin_bit_cast(unsigned, f);
    return (u + 0x7FFFu + ((u >> 16) & 1u)) >> 16;   // RNE fp32->bf16
}

// Fragment-linear bf16 layout: 16B chunk = ((row>>4)*8 + (c>>3))*16 + (row&15),
// element = c&7.  One ds_read_b128 per MFMA fragment, conflict-free.
union SM {
    struct {
        short l[W_ * C_];    // 64 KiB
        short r[W_ * C_];    // 64 KiB
    } st;
    float out_s[CH0 * PAD];  // 100.5 KiB (aliased after compute)
};

__global__ __launch_bounds__(1024, 4) void cost_volume_kernel(
    const float* __restrict__ L, const float* __restrict__ R,
    float* __restrict__ out)
{
    __shared__ SM sm;
    const int tid = threadIdx.x;
    const int h   = blockIdx.x;
    const int b   = blockIdx.y;
    const size_t in_base = (((size_t)b * C_) * H_ + h) * (size_t)W_;

    // ---- stage L (x 1/64 folded in) and R: 512 rows x 64 c, fp32->bf16 ----
    {
        const int wl = tid & 511;           // row (w for L, u for R)
        const int ch = tid >> 9;            // 0..1
        const int m  = wl & 15, wq = wl >> 4;
        const float* lp = L + in_base + wl;
        const float* rp = R + in_base + wl;
        #pragma unroll
        for (int i = 0; i < 4; ++i) {
            const int cc = ch + 2 * i;      // c-chunk 0..7 across (ch,i)
            unsigned dl[4], dr[4];
            #pragma unroll
            for (int jj = 0; jj < 4; ++jj) {
                float l0 = lp[(size_t)(cc * 8 + 2 * jj)     * HW] * 0.015625f;
                float l1 = lp[(size_t)(cc * 8 + 2 * jj + 1) * HW] * 0.015625f;
                float r0 = rp[(size_t)(cc * 8 + 2 * jj)     * HW];
                float r1 = rp[(size_t)(cc * 8 + 2 * jj + 1) * HW];
                dl[jj] = f2bf(l0) | (f2bf(l1) << 16);
                dr[jj] = f2bf(r0) | (f2bf(r1) << 16);
            }
            const int chunk = (wq * 8 + cc) * 16 + m;
            *((uint4*)&sm.st.l[chunk * 8]) = make_uint4(dl[0], dl[1], dl[2], dl[3]);
            *((uint4*)&sm.st.r[chunk * 8]) = make_uint4(dr[0], dr[1], dr[2], dr[3]);
        }
    }
    __syncthreads();

    // ---- banded GEMM: wave wv owns w-tiles wv and wv+16 ----
    const int lane = tid & 63;
    const int wv   = tid >> 6;          // 0..15
    const int q    = lane >> 4, m16 = lane & 15;
    const short8* lv = (const short8*)sm.st.l;
    const short8* rv = (const short8*)sm.st.r;

    floatx4 acc[2][7];
    #pragma unroll
    for (int half = 0; half < 2; ++half) {
        const int wt = wv + 16 * half;
        const short8 a0 = lv[(wt * 8 +     q) * 16 + m16];
        const short8 a1 = lv[(wt * 8 + 4 + q) * 16 + m16];
        #pragma unroll
        for (int t = 0; t < 7; ++t) {
            floatx4 c = {0.f, 0.f, 0.f, 0.f};
            const int ut = wt + t - 3;            // u-tile; OOB -> zero plane
            if ((unsigned)ut < (unsigned)NWT) {   // wave-uniform branch
                const short8 b0 = rv[(ut * 8 +     q) * 16 + m16];
                const short8 b1 = rv[(ut * 8 + 4 + q) * 16 + m16];
                c = __builtin_amdgcn_mfma_f32_16x16x32_bf16(a0, b0, c, 0, 0, 0);
                c = __builtin_amdgcn_mfma_f32_16x16x32_bf16(a1, b1, c, 0, 0, 0);
            }
            acc[half][t] = c;
        }
    }

    // ---- epilogue: two d-chunks through aliased LDS, coalesced stores ----
    // C/D layout: col(u)=lane&15, row(w)=(lane>>4)*4+reg; d_idx = d+48.
    float* ob = out + (((size_t)b * ND) * H_ + h) * (size_t)W_;
    int lo = 0;
    #pragma unroll
    for (int ck = 0; ck < 2; ++ck) {
        const int cnt = ck ? (ND - CH0) : CH0;
        __syncthreads();    // staging (ck=0) / prev chunk reads (ck=1) done
        #pragma unroll
        for (int half = 0; half < 2; ++half) {
            const int wt = wv + 16 * half;
            #pragma unroll
            for (int t = 0; t < 7; ++t) {
                #pragma unroll
                for (int r = 0; r < 4; ++r) {
                    const int ml    = q * 4 + r;
                    const int d_idx = ml - m16 + 96 - 16 * t;
                    const int drel  = d_idx - lo;
                    if ((unsigned)drel < (unsigned)cnt)
                        sm.out_s[drel * PAD + wt * 16 + ml] = acc[half][t][r];
                }
            }
        }
        __syncthreads();
        for (int i = tid; i < cnt * W_; i += 1024) {
            const int pr = i >> 9, w = i & 511;
            ob[(size_t)(lo + pr) * HW + w] = sm.out_s[pr * PAD + w];
        }
        lo += CH0;
    }
}

extern "C" void kernel_launch(void* const* d_in, const int* in_sizes, int n_in,
                              void* d_out, int out_size, void* d_ws, size_t ws_size,
                              hipStream_t stream) {
    const float* L = (const float*)d_in[0];
    const float* R = (const float*)d_in[1];
    float* out = (float*)d_out;
    (void)in_sizes; (void)n_in; (void)d_ws; (void)ws_size; (void)out_size;
    dim3 grid(H_, B_);   // one block per (b,h) row
    hipLaunchKernelGGL(cost_volume_kernel, grid, dim3(1024), 0, stream, L, R, out);
}